// Round 2
// baseline (1540.555 us; speedup 1.0000x reference)
//
#include <hip/hip_runtime.h>
#include <hip/hip_bf16.h>
#include <stdint.h>

#define NN 100000
#define EE 1600000
#define DD 128
#define EPSV 1e-5f

typedef __attribute__((ext_vector_type(8))) short short8;
typedef __attribute__((ext_vector_type(4))) float floatx4;
typedef unsigned short u16;

union S8 { short8 v; short s[8]; unsigned short u[8]; };

__device__ __forceinline__ float bf2f(u16 u) {
    return __uint_as_float(((unsigned int)u) << 16);
}
__device__ __forceinline__ u16 f2bf(float f) {
    unsigned int x = __float_as_uint(f);
    x += 0x7FFFu + ((x >> 16) & 1u);
    return (u16)(x >> 16);
}

// ---------------------------------------------------------------------------
// ws layout (bytes):
//   agg      fp32 [NN*DD]   @ 0            (51,200,000)
//   t        bf16 [NN*DD]   @ 51,200,000   (25,600,000)
//   feats_c  bf16 [NN*DD]   @ 76,800,000   (25,600,000)  (used only if fp32 in)
//   params_c bf16 [33408]   @ 102,400,000  (66,816)
//   stats    fp32 [5*DD]    @ 102,466,816  (2,560)
//   flag     int32          @ 102,469,376  (4)           1 = inputs are fp32
// params_c offsets (elements): Wg 0, Wr 16384, bg 32768, br 32896,
//                              g1 33024, g2 33152, be2 33280
// ---------------------------------------------------------------------------

// ------------- dtype detection: fp32 vs bf16 --------------------------------
// fp32 N(0,1) values read as fp32 fall in (1e-3,1e3) w.p. ~0.999/lane.
// bf16 pairs read as fp32 get their exponent byte from the 2nd bf16's low
// bits -> |x| >= ~6e35 or <= ~9e-38, never in the window.
__global__ void k_detect(const float* __restrict__ f, int* __restrict__ flag) {
    __shared__ int cnt;
    if (threadIdx.x == 0) cnt = 0;
    __syncthreads();
    const float v = fabsf(f[threadIdx.x]);
    const int ok = (v > 1e-3f && v < 1e3f) ? 1 : 0;
    if (ok) atomicAdd(&cnt, 1);
    __syncthreads();
    if (threadIdx.x == 0) *flag = (cnt >= 128) ? 1 : 0;
}

// ------------- fp32 -> bf16 canonicalization (no-op for bf16 inputs) --------
__global__ __launch_bounds__(256) void k_convert_feats(
    const int* __restrict__ flag, const float* __restrict__ ff,
    u16* __restrict__ fc)
{
    if (*flag == 0) return;
    const size_t P = (size_t)NN * (DD / 2);
    for (size_t i = (size_t)blockIdx.x * blockDim.x + threadIdx.x; i < P;
         i += (size_t)gridDim.x * blockDim.x) {
        const float2 v = *(const float2*)(ff + 2 * i);
        const unsigned int o = (unsigned int)f2bf(v.x) | ((unsigned int)f2bf(v.y) << 16);
        *(unsigned int*)(fc + 2 * i) = o;
    }
}

__global__ __launch_bounds__(256) void k_convert_params(
    const int* __restrict__ flag,
    const float* __restrict__ Wg, const float* __restrict__ Wr,
    const float* __restrict__ bg, const float* __restrict__ br,
    const float* __restrict__ g1, const float* __restrict__ g2,
    const float* __restrict__ be2, u16* __restrict__ pc)
{
    if (*flag == 0) return;
    const int i = blockIdx.x * blockDim.x + threadIdx.x;
    if (i >= 33408) return;
    float v;
    if (i < 16384)      v = Wg[i];
    else if (i < 32768) v = Wr[i - 16384];
    else {
        const int j = i - 32768;
        const int a = j >> 7, o = j & 127;
        v = (a == 0) ? bg[o] : (a == 1) ? br[o] : (a == 2) ? g1[o]
          : (a == 3) ? g2[o] : be2[o];
    }
    pc[i] = f2bf(v);
}

// ---------------- Kernel A: scatter-add aggregation -------------------------
__global__ __launch_bounds__(256) void k_aggregate(
    const int* __restrict__ flag,
    const u16* __restrict__ feats_raw, const u16* __restrict__ feats_c,
    const int* __restrict__ src, const int* __restrict__ dst,
    float* __restrict__ agg)
{
    const u16* __restrict__ F = (*flag != 0) ? feats_c : feats_raw;
    const int lane = threadIdx.x & 63;
    const int wave = (blockIdx.x * blockDim.x + threadIdx.x) >> 6;
    const int nw   = (gridDim.x * blockDim.x) >> 6;
    for (int e = wave; e < EE; e += nw) {
        const int s = src[e];
        const int d = dst[e];
        const unsigned int v = *(const unsigned int*)(F + (size_t)s * DD + lane * 2);
        float* p = agg + (size_t)d * DD + lane * 2;
        unsafeAtomicAdd(p,     bf2f((u16)(v & 0xFFFFu)));
        unsafeAtomicAdd(p + 1, bf2f((u16)(v >> 16)));
    }
}

// ---------------- Kernel B: fused dual GEMM + relu + add --------------------
// t = relu(agg@Wg + bg) + relu(feats@Wr + br), stored bf16.
__global__ __launch_bounds__(256) void k_gemm(
    const int* __restrict__ flag,
    const float* __restrict__ agg,
    const u16* __restrict__ feats_raw, const u16* __restrict__ feats_c,
    const u16* __restrict__ Wg_raw, const u16* __restrict__ bg_raw,
    const u16* __restrict__ Wr_raw, const u16* __restrict__ br_raw,
    const u16* __restrict__ pc,
    u16* __restrict__ t_out)
{
    const bool f32 = (*flag != 0);
    const u16* __restrict__ F  = f32 ? feats_c     : feats_raw;
    const u16* __restrict__ Wg = f32 ? pc          : Wg_raw;
    const u16* __restrict__ Wr = f32 ? pc + 16384  : Wr_raw;
    const u16* __restrict__ bg = f32 ? pc + 32768  : bg_raw;
    const u16* __restrict__ br = f32 ? pc + 32896  : br_raw;

    const int lane = threadIdx.x & 63;
    const int wv   = threadIdx.x >> 6;
    const int l15  = lane & 15;
    const int quad = lane >> 4;
    const int c0 = wv * 16 + l15;
    const int c1 = 64 + wv * 16 + l15;

    // B-operand layout (16x16x32): lane holds B[k = quad*8 + j][n = lane&15]
    S8 fg0[4], fg1[4], fr0[4], fr1[4];
#pragma unroll
    for (int kb = 0; kb < 4; ++kb) {
        const int kr = kb * 32 + quad * 8;
#pragma unroll
        for (int j = 0; j < 8; ++j) {
            fg0[kb].u[j] = Wg[(size_t)(kr + j) * DD + c0];
            fg1[kb].u[j] = Wg[(size_t)(kr + j) * DD + c1];
            fr0[kb].u[j] = Wr[(size_t)(kr + j) * DD + c0];
            fr1[kb].u[j] = Wr[(size_t)(kr + j) * DD + c1];
        }
    }
    const float bgc0 = bf2f(bg[c0]), bgc1 = bf2f(bg[c1]);
    const float brc0 = bf2f(br[c0]), brc1 = bf2f(br[c1]);

    for (int tile = blockIdx.x; tile < NN / 16; tile += gridDim.x) {
        const int row0 = tile * 16;
        const int arow = row0 + l15;  // A layout: lane holds A[m=lane&15][k=quad*8+j]
        floatx4 ag0 = {0.f,0.f,0.f,0.f}, ag1 = {0.f,0.f,0.f,0.f};
        floatx4 ar0 = {0.f,0.f,0.f,0.f}, ar1 = {0.f,0.f,0.f,0.f};
#pragma unroll
        for (int kb = 0; kb < 4; ++kb) {
            const int kbase = kb * 32 + quad * 8;
            const float* ap = agg + (size_t)arow * DD + kbase;
            const floatx4 a0 = *(const floatx4*)ap;
            const floatx4 a1 = *(const floatx4*)(ap + 4);
            S8 af;
#pragma unroll
            for (int j = 0; j < 4; ++j) {
                af.u[j]     = f2bf(a0[j]);
                af.u[4 + j] = f2bf(a1[j]);
            }
            S8 ff;
            ff.v = *(const short8*)(F + (size_t)arow * DD + kbase);
            ag0 = __builtin_amdgcn_mfma_f32_16x16x32_bf16(af.v, fg0[kb].v, ag0, 0, 0, 0);
            ag1 = __builtin_amdgcn_mfma_f32_16x16x32_bf16(af.v, fg1[kb].v, ag1, 0, 0, 0);
            ar0 = __builtin_amdgcn_mfma_f32_16x16x32_bf16(ff.v, fr0[kb].v, ar0, 0, 0, 0);
            ar1 = __builtin_amdgcn_mfma_f32_16x16x32_bf16(ff.v, fr1[kb].v, ar1, 0, 0, 0);
        }
        // C/D layout: col = lane&15, row = quad*4 + reg  [verified m89/m91]
#pragma unroll
        for (int r = 0; r < 4; ++r) {
            const int row = row0 + quad * 4 + r;
            const float t0 = fmaxf(ag0[r] + bgc0, 0.f) + fmaxf(ar0[r] + brc0, 0.f);
            const float t1 = fmaxf(ag1[r] + bgc1, 0.f) + fmaxf(ar1[r] + brc1, 0.f);
            t_out[(size_t)row * DD + c0] = f2bf(t0);
            t_out[(size_t)row * DD + c1] = f2bf(t1);
        }
    }
}

// ---------------- Kernel C: column stats (St, Stt, Sf, Sff, Stf) ------------
__global__ __launch_bounds__(256) void k_stats(
    const int* __restrict__ flag,
    const u16* __restrict__ t,
    const u16* __restrict__ feats_raw, const u16* __restrict__ feats_c,
    float* __restrict__ stats)
{
    const u16* __restrict__ F = (*flag != 0) ? feats_c : feats_raw;
    const int tx = threadIdx.x;
    const int c2 = (tx & 63) * 2;
    const int rg = tx >> 6;
    float acc[10];
#pragma unroll
    for (int k = 0; k < 10; ++k) acc[k] = 0.f;

    for (int r = blockIdx.x * 4 + rg; r < NN; r += gridDim.x * 4) {
        const unsigned int tv = *(const unsigned int*)(t + (size_t)r * DD + c2);
        const unsigned int fv = *(const unsigned int*)(F + (size_t)r * DD + c2);
        const float t0 = bf2f((u16)(tv & 0xFFFFu));
        const float t1 = bf2f((u16)(tv >> 16));
        const float f0 = bf2f((u16)(fv & 0xFFFFu));
        const float f1 = bf2f((u16)(fv >> 16));
        acc[0] += t0;      acc[1] += t1;
        acc[2] += t0 * t0; acc[3] += t1 * t1;
        acc[4] += f0;      acc[5] += f1;
        acc[6] += f0 * f0; acc[7] += f1 * f1;
        acc[8] += t0 * f0; acc[9] += t1 * f1;
    }

    __shared__ float red[256][10];
#pragma unroll
    for (int k = 0; k < 10; ++k) red[tx][k] = acc[k];
    __syncthreads();
    if (tx < 64) {
#pragma unroll
        for (int k = 0; k < 10; ++k) {
            const float v = red[tx][k] + red[tx + 64][k] + red[tx + 128][k] + red[tx + 192][k];
            unsafeAtomicAdd(&stats[(k >> 1) * DD + c2 + (k & 1)], v);
        }
    }
}

// ---------------- Kernel D: fused BN1+residual+BN2 elementwise --------------
// out = alpha_c * t + beta_c * f + gamma_c  (both BNs folded; be1 cancels)
__global__ __launch_bounds__(256) void k_final(
    const int* __restrict__ flag,
    const u16* __restrict__ t,
    const u16* __restrict__ feats_raw, const u16* __restrict__ feats_c,
    const u16* __restrict__ g1_raw, const u16* __restrict__ g2_raw,
    const u16* __restrict__ be2_raw, const u16* __restrict__ pc,
    const float* __restrict__ stats,
    void* __restrict__ out)
{
    const bool f32 = (*flag != 0);
    const u16* __restrict__ F   = f32 ? feats_c    : feats_raw;
    const u16* __restrict__ g1  = f32 ? pc + 33024 : g1_raw;
    const u16* __restrict__ g2  = f32 ? pc + 33152 : g2_raw;
    const u16* __restrict__ be2 = f32 ? pc + 33280 : be2_raw;

    __shared__ float sA[DD], sB[DD], sG[DD];
    if (threadIdx.x < DD) {
        const int c = threadIdx.x;
        const float invN = 1.0f / (float)NN;
        const float St  = stats[c],          Stt = stats[DD + c];
        const float Sf  = stats[2 * DD + c], Sff = stats[3 * DD + c];
        const float Stf = stats[4 * DD + c];
        const float mu1  = St * invN;
        const float vart = fmaxf(Stt * invN - mu1 * mu1, 0.f);
        const float muf  = Sf * invN;
        const float varf = fmaxf(Sff * invN - muf * muf, 0.f);
        const float cov  = Stf * invN - mu1 * muf;
        const float r1   = rsqrtf(vart + EPSV);
        const float a1   = bf2f(g1[c]) * r1;
        const float var2 = fmaxf(a1 * a1 * vart + 2.f * a1 * cov + varf, 0.f);
        const float r2   = rsqrtf(var2 + EPSV);
        const float g2r2 = bf2f(g2[c]) * r2;
        sA[c] = g2r2 * a1;
        sB[c] = g2r2;
        sG[c] = bf2f(be2[c]) - g2r2 * (a1 * mu1 + muf);
    }
    __syncthreads();

    float* outf = (float*)out;
    u16*   outb = (u16*)out;
    const size_t P = (size_t)NN * (DD / 2);
    for (size_t i = (size_t)blockIdx.x * blockDim.x + threadIdx.x; i < P;
         i += (size_t)gridDim.x * blockDim.x) {
        const int c = ((int)(i & 63)) * 2;
        const unsigned int tv = *(const unsigned int*)(t + 2 * i);
        const unsigned int fv = *(const unsigned int*)(F + 2 * i);
        const float o0 = sA[c]     * bf2f((u16)(tv & 0xFFFFu))
                       + sB[c]     * bf2f((u16)(fv & 0xFFFFu)) + sG[c];
        const float o1 = sA[c + 1] * bf2f((u16)(tv >> 16))
                       + sB[c + 1] * bf2f((u16)(fv >> 16)) + sG[c + 1];
        if (f32) {
            float2 o; o.x = o0; o.y = o1;
            *(float2*)(outf + 2 * i) = o;
        } else {
            const unsigned int ov = (unsigned int)f2bf(o0) | ((unsigned int)f2bf(o1) << 16);
            *(unsigned int*)(outb + 2 * i) = ov;
        }
    }
}

extern "C" void kernel_launch(void* const* d_in, const int* in_sizes, int n_in,
                              void* d_out, int out_size, void* d_ws, size_t ws_size,
                              hipStream_t stream) {
    const u16* feats = (const u16*)d_in[0];
    const u16* Wg    = (const u16*)d_in[1];
    const u16* bg    = (const u16*)d_in[2];
    const u16* Wr    = (const u16*)d_in[3];
    const u16* br    = (const u16*)d_in[4];
    const u16* g1    = (const u16*)d_in[5];
    // d_in[6] = be1: cancels algebraically, unused
    const u16* g2    = (const u16*)d_in[7];
    const u16* be2   = (const u16*)d_in[8];
    const int* src = (const int*)d_in[9];
    const int* dst = (const int*)d_in[10];

    char* ws = (char*)d_ws;
    float* agg     = (float*)ws;                       // 51,200,000 B
    u16*   t       = (u16*)  (ws + 51200000);          // 25,600,000 B
    u16*   feats_c = (u16*)  (ws + 76800000);          // 25,600,000 B
    u16*   pc      = (u16*)  (ws + 102400000);         //     66,816 B
    float* stats   = (float*)(ws + 102466816);         //      2,560 B
    int*   flag    = (int*)  (ws + 102469376);         //          4 B

    hipMemsetAsync(agg,   0, (size_t)NN * DD * sizeof(float), stream);
    hipMemsetAsync(stats, 0, 5 * DD * sizeof(float), stream);

    k_detect<<<1, 256, 0, stream>>>((const float*)d_in[0], flag);
    k_convert_feats<<<1024, 256, 0, stream>>>(flag, (const float*)d_in[0], feats_c);
    k_convert_params<<<131, 256, 0, stream>>>(flag,
        (const float*)d_in[1], (const float*)d_in[3], (const float*)d_in[2],
        (const float*)d_in[4], (const float*)d_in[5], (const float*)d_in[7],
        (const float*)d_in[8], pc);

    k_aggregate<<<2048, 256, 0, stream>>>(flag, feats, feats_c, src, dst, agg);
    k_gemm     <<<1024, 256, 0, stream>>>(flag, agg, feats, feats_c, Wg, bg, Wr, br, pc, t);
    k_stats    <<<200,  256, 0, stream>>>(flag, t, feats, feats_c, stats);
    k_final    <<<2048, 256, 0, stream>>>(flag, t, feats, feats_c, g1, g2, be2, pc, stats, d_out);
}

// Round 3
// 567.048 us; speedup vs baseline: 2.7168x; 2.7168x over previous
//
#include <hip/hip_runtime.h>
#include <hip/hip_bf16.h>
#include <stdint.h>

#define NN 100000
#define EE 1600000
#define DD 128
#define EPSV 1e-5f

typedef __attribute__((ext_vector_type(8))) short short8;
typedef __attribute__((ext_vector_type(4))) float floatx4;
typedef unsigned short u16;

union S8 { short8 v; short s[8]; unsigned short u[8]; };

__device__ __forceinline__ float bf2f(u16 u) {
    return __uint_as_float(((unsigned int)u) << 16);
}
__device__ __forceinline__ u16 f2bf(float f) {
    unsigned int x = __float_as_uint(f);
    x += 0x7FFFu + ((x >> 16) & 1u);
    return (u16)(x >> 16);
}

// ---------------------------------------------------------------------------
// ws layout (bytes):
//   aggb     bf16 [NN*DD]  @ 0           (25,600,000)   sum-aggregated feats
//   t        bf16 [NN*DD]  @ 25,600,000  (25,600,000)
//   feats_c  bf16 [NN*DD]  @ 51,200,000  (25,600,000)   (only if fp32 inputs)
//   pc       bf16 [33408]  @ 76,800,000  (66,816)       canonical params
//   stats    fp32 [5*DD]   @ 76,866,816  (2,560)
//   flag     int32         @ 76,869,376  (4)            1 = inputs are fp32
//   counts   int  [NN]     @ 76,869,632  (400,000)
//   row_st   int  [NN]     @ 77,269,632  (400,000)
//   cursor   int  [NN]     @ 77,669,632  (400,000)
//   edge_s   int  [EE]     @ 78,069,632  (6,400,000)    src grouped by dst
// pc offsets (elem): Wg 0, Wr 16384, bg 32768, br 32896, g1 33024,
//                    g2 33152, be2 33280
// ---------------------------------------------------------------------------

// ------------- dtype detection: fp32 vs bf16 --------------------------------
__global__ void k_detect(const float* __restrict__ f, int* __restrict__ flag) {
    __shared__ int cnt;
    if (threadIdx.x == 0) cnt = 0;
    __syncthreads();
    const float v = fabsf(f[threadIdx.x]);
    if (v > 1e-3f && v < 1e3f) atomicAdd(&cnt, 1);
    __syncthreads();
    if (threadIdx.x == 0) *flag = (cnt >= 128) ? 1 : 0;
}

// ------------- fp32 -> bf16 canonicalization (no-op for bf16 inputs) --------
__global__ __launch_bounds__(256) void k_convert_feats(
    const int* __restrict__ flag, const float* __restrict__ ff,
    u16* __restrict__ fc)
{
    if (*flag == 0) return;
    const size_t P = (size_t)NN * (DD / 2);
    for (size_t i = (size_t)blockIdx.x * blockDim.x + threadIdx.x; i < P;
         i += (size_t)gridDim.x * blockDim.x) {
        const float2 v = *(const float2*)(ff + 2 * i);
        const unsigned int o = (unsigned int)f2bf(v.x) | ((unsigned int)f2bf(v.y) << 16);
        *(unsigned int*)(fc + 2 * i) = o;
    }
}

__global__ __launch_bounds__(256) void k_convert_params(
    const int* __restrict__ flag,
    const float* __restrict__ Wg, const float* __restrict__ Wr,
    const float* __restrict__ bg, const float* __restrict__ br,
    const float* __restrict__ g1, const float* __restrict__ g2,
    const float* __restrict__ be2, u16* __restrict__ pc)
{
    if (*flag == 0) return;
    const int i = blockIdx.x * blockDim.x + threadIdx.x;
    if (i >= 33408) return;
    float v;
    if (i < 16384)      v = Wg[i];
    else if (i < 32768) v = Wr[i - 16384];
    else {
        const int j = i - 32768;
        const int a = j >> 7, o = j & 127;
        v = (a == 0) ? bg[o] : (a == 1) ? br[o] : (a == 2) ? g1[o]
          : (a == 3) ? g2[o] : be2[o];
    }
    pc[i] = f2bf(v);
}

// ---------------- CSR build: histogram -> scan -> fill ----------------------
__global__ __launch_bounds__(256) void k_hist(
    const int* __restrict__ dst, int* __restrict__ counts)
{
    const int stride = gridDim.x * blockDim.x;
    for (int e = blockIdx.x * blockDim.x + threadIdx.x; e < EE; e += stride)
        atomicAdd(&counts[dst[e]], 1);
}

// single-block exclusive scan of counts -> row_st (+ cursor copy)
__global__ __launch_bounds__(1024) void k_scan(
    const int* __restrict__ counts, int* __restrict__ row_st,
    int* __restrict__ cursor)
{
    const int tx = threadIdx.x;
    const int lane = tx & 63, w = tx >> 6;
    __shared__ int wsum[16];
    __shared__ int carry;
    if (tx == 0) carry = 0;
    __syncthreads();
    for (int base = 0; base < NN; base += 1024) {
        const int i = base + tx;
        const int v = (i < NN) ? counts[i] : 0;
        int incl = v;
#pragma unroll
        for (int d = 1; d < 64; d <<= 1) {
            const int n = __shfl_up(incl, d, 64);
            if (lane >= d) incl += n;
        }
        if (lane == 63) wsum[w] = incl;
        __syncthreads();
        if (tx < 16) {
            int s = wsum[tx];
#pragma unroll
            for (int d = 1; d < 16; d <<= 1) {
                const int n = __shfl_up(s, d, 16);
                if ((tx & 15) >= d) s += n;
            }
            wsum[tx] = s;  // inclusive wave-sums
        }
        __syncthreads();
        const int c = carry;
        const int woff = (w == 0) ? 0 : wsum[w - 1];
        if (i < NN) {
            const int excl = c + woff + incl - v;
            row_st[i] = excl;
            cursor[i] = excl;
        }
        __syncthreads();
        if (tx == 0) carry = c + wsum[15];
    }
}

__global__ __launch_bounds__(256) void k_fill(
    const int* __restrict__ src, const int* __restrict__ dst,
    int* __restrict__ cursor, int* __restrict__ edge_s)
{
    const int stride = gridDim.x * blockDim.x;
    for (int e = blockIdx.x * blockDim.x + threadIdx.x; e < EE; e += stride) {
        const int d = dst[e];
        const int pos = atomicAdd(&cursor[d], 1);
        edge_s[pos] = src[e];
    }
}

// ---------------- Kernel A': gather aggregation (no feature atomics) --------
// one wave per dst node; lane owns cols {2*lane, 2*lane+1}; edges batched
// 64-wide into lanes then shfl-broadcast 4 at a time for MLP.
__global__ __launch_bounds__(256) void k_gather(
    const int* __restrict__ flag,
    const u16* __restrict__ feats_raw, const u16* __restrict__ feats_c,
    const int* __restrict__ edge_s, const int* __restrict__ row_st,
    const int* __restrict__ counts,
    u16* __restrict__ aggb)
{
    const u16* __restrict__ F = (*flag != 0) ? feats_c : feats_raw;
    const int lane = threadIdx.x & 63;
    const int wave = (blockIdx.x * blockDim.x + threadIdx.x) >> 6;
    const int nw   = (gridDim.x * blockDim.x) >> 6;
    for (int node = wave; node < NN; node += nw) {
        const int rs  = row_st[node];
        const int deg = counts[node];
        float a0 = 0.f, a1 = 0.f;
        for (int base = 0; base < deg; base += 64) {
            const int rem = deg - base;
            const int nb  = rem < 64 ? rem : 64;
            int idx = 0;
            if (lane < nb) idx = edge_s[rs + base + lane];
            int j = 0;
            for (; j + 4 <= nb; j += 4) {
                const int s0 = __shfl(idx, j,     64);
                const int s1 = __shfl(idx, j + 1, 64);
                const int s2 = __shfl(idx, j + 2, 64);
                const int s3 = __shfl(idx, j + 3, 64);
                const unsigned int v0 = *(const unsigned int*)(F + (size_t)s0 * DD + lane * 2);
                const unsigned int v1 = *(const unsigned int*)(F + (size_t)s1 * DD + lane * 2);
                const unsigned int v2 = *(const unsigned int*)(F + (size_t)s2 * DD + lane * 2);
                const unsigned int v3 = *(const unsigned int*)(F + (size_t)s3 * DD + lane * 2);
                a0 += bf2f((u16)(v0 & 0xFFFFu)) + bf2f((u16)(v1 & 0xFFFFu))
                    + bf2f((u16)(v2 & 0xFFFFu)) + bf2f((u16)(v3 & 0xFFFFu));
                a1 += bf2f((u16)(v0 >> 16)) + bf2f((u16)(v1 >> 16))
                    + bf2f((u16)(v2 >> 16)) + bf2f((u16)(v3 >> 16));
            }
            for (; j < nb; ++j) {
                const int s0 = __shfl(idx, j, 64);
                const unsigned int v0 = *(const unsigned int*)(F + (size_t)s0 * DD + lane * 2);
                a0 += bf2f((u16)(v0 & 0xFFFFu));
                a1 += bf2f((u16)(v0 >> 16));
            }
        }
        const unsigned int o = (unsigned int)f2bf(a0) | ((unsigned int)f2bf(a1) << 16);
        *(unsigned int*)(aggb + (size_t)node * DD + lane * 2) = o;
    }
}

// ---------------- Kernel B: fused dual GEMM + relu + add --------------------
// t = relu(agg@Wg + bg) + relu(feats@Wr + br), stored bf16. agg is bf16 now.
__global__ __launch_bounds__(256) void k_gemm(
    const int* __restrict__ flag,
    const u16* __restrict__ aggb,
    const u16* __restrict__ feats_raw, const u16* __restrict__ feats_c,
    const u16* __restrict__ Wg_raw, const u16* __restrict__ bg_raw,
    const u16* __restrict__ Wr_raw, const u16* __restrict__ br_raw,
    const u16* __restrict__ pc,
    u16* __restrict__ t_out)
{
    const bool f32 = (*flag != 0);
    const u16* __restrict__ F  = f32 ? feats_c     : feats_raw;
    const u16* __restrict__ Wg = f32 ? pc          : Wg_raw;
    const u16* __restrict__ Wr = f32 ? pc + 16384  : Wr_raw;
    const u16* __restrict__ bg = f32 ? pc + 32768  : bg_raw;
    const u16* __restrict__ br = f32 ? pc + 32896  : br_raw;

    const int lane = threadIdx.x & 63;
    const int wv   = threadIdx.x >> 6;
    const int l15  = lane & 15;
    const int quad = lane >> 4;
    const int c0 = wv * 16 + l15;
    const int c1 = 64 + wv * 16 + l15;

    // B-operand layout (16x16x32): lane holds B[k = quad*8 + j][n = lane&15]
    S8 fg0[4], fg1[4], fr0[4], fr1[4];
#pragma unroll
    for (int kb = 0; kb < 4; ++kb) {
        const int kr = kb * 32 + quad * 8;
#pragma unroll
        for (int j = 0; j < 8; ++j) {
            fg0[kb].u[j] = Wg[(size_t)(kr + j) * DD + c0];
            fg1[kb].u[j] = Wg[(size_t)(kr + j) * DD + c1];
            fr0[kb].u[j] = Wr[(size_t)(kr + j) * DD + c0];
            fr1[kb].u[j] = Wr[(size_t)(kr + j) * DD + c1];
        }
    }
    const float bgc0 = bf2f(bg[c0]), bgc1 = bf2f(bg[c1]);
    const float brc0 = bf2f(br[c0]), brc1 = bf2f(br[c1]);

    for (int tile = blockIdx.x; tile < NN / 16; tile += gridDim.x) {
        const int row0 = tile * 16;
        const int arow = row0 + l15;  // A layout: lane holds A[m=lane&15][k=quad*8+j]
        floatx4 ag0 = {0.f,0.f,0.f,0.f}, ag1 = {0.f,0.f,0.f,0.f};
        floatx4 ar0 = {0.f,0.f,0.f,0.f}, ar1 = {0.f,0.f,0.f,0.f};
#pragma unroll
        for (int kb = 0; kb < 4; ++kb) {
            const int kbase = kb * 32 + quad * 8;
            S8 av, ff;
            av.v = *(const short8*)(aggb + (size_t)arow * DD + kbase);
            ff.v = *(const short8*)(F    + (size_t)arow * DD + kbase);
            ag0 = __builtin_amdgcn_mfma_f32_16x16x32_bf16(av.v, fg0[kb].v, ag0, 0, 0, 0);
            ag1 = __builtin_amdgcn_mfma_f32_16x16x32_bf16(av.v, fg1[kb].v, ag1, 0, 0, 0);
            ar0 = __builtin_amdgcn_mfma_f32_16x16x32_bf16(ff.v, fr0[kb].v, ar0, 0, 0, 0);
            ar1 = __builtin_amdgcn_mfma_f32_16x16x32_bf16(ff.v, fr1[kb].v, ar1, 0, 0, 0);
        }
        // C/D layout: col = lane&15, row = quad*4 + reg  [verified m89/m91]
#pragma unroll
        for (int r = 0; r < 4; ++r) {
            const int row = row0 + quad * 4 + r;
            const float t0 = fmaxf(ag0[r] + bgc0, 0.f) + fmaxf(ar0[r] + brc0, 0.f);
            const float t1 = fmaxf(ag1[r] + bgc1, 0.f) + fmaxf(ar1[r] + brc1, 0.f);
            t_out[(size_t)row * DD + c0] = f2bf(t0);
            t_out[(size_t)row * DD + c1] = f2bf(t1);
        }
    }
}

// ---------------- Kernel C: column stats (St, Stt, Sf, Sff, Stf) ------------
__global__ __launch_bounds__(256) void k_stats(
    const int* __restrict__ flag,
    const u16* __restrict__ t,
    const u16* __restrict__ feats_raw, const u16* __restrict__ feats_c,
    float* __restrict__ stats)
{
    const u16* __restrict__ F = (*flag != 0) ? feats_c : feats_raw;
    const int tx = threadIdx.x;
    const int c2 = (tx & 63) * 2;
    const int rg = tx >> 6;
    float acc[10];
#pragma unroll
    for (int k = 0; k < 10; ++k) acc[k] = 0.f;

    for (int r = blockIdx.x * 4 + rg; r < NN; r += gridDim.x * 4) {
        const unsigned int tv = *(const unsigned int*)(t + (size_t)r * DD + c2);
        const unsigned int fv = *(const unsigned int*)(F + (size_t)r * DD + c2);
        const float t0 = bf2f((u16)(tv & 0xFFFFu));
        const float t1 = bf2f((u16)(tv >> 16));
        const float f0 = bf2f((u16)(fv & 0xFFFFu));
        const float f1 = bf2f((u16)(fv >> 16));
        acc[0] += t0;      acc[1] += t1;
        acc[2] += t0 * t0; acc[3] += t1 * t1;
        acc[4] += f0;      acc[5] += f1;
        acc[6] += f0 * f0; acc[7] += f1 * f1;
        acc[8] += t0 * f0; acc[9] += t1 * f1;
    }

    __shared__ float red[256][10];
#pragma unroll
    for (int k = 0; k < 10; ++k) red[tx][k] = acc[k];
    __syncthreads();
    if (tx < 64) {
#pragma unroll
        for (int k = 0; k < 10; ++k) {
            const float v = red[tx][k] + red[tx + 64][k] + red[tx + 128][k] + red[tx + 192][k];
            unsafeAtomicAdd(&stats[(k >> 1) * DD + c2 + (k & 1)], v);
        }
    }
}

// ---------------- Kernel D: fused BN1+residual+BN2 elementwise --------------
__global__ __launch_bounds__(256) void k_final(
    const int* __restrict__ flag,
    const u16* __restrict__ t,
    const u16* __restrict__ feats_raw, const u16* __restrict__ feats_c,
    const u16* __restrict__ g1_raw, const u16* __restrict__ g2_raw,
    const u16* __restrict__ be2_raw, const u16* __restrict__ pc,
    const float* __restrict__ stats,
    void* __restrict__ out)
{
    const bool f32 = (*flag != 0);
    const u16* __restrict__ F   = f32 ? feats_c    : feats_raw;
    const u16* __restrict__ g1  = f32 ? pc + 33024 : g1_raw;
    const u16* __restrict__ g2  = f32 ? pc + 33152 : g2_raw;
    const u16* __restrict__ be2 = f32 ? pc + 33280 : be2_raw;

    __shared__ float sA[DD], sB[DD], sG[DD];
    if (threadIdx.x < DD) {
        const int c = threadIdx.x;
        const float invN = 1.0f / (float)NN;
        const float St  = stats[c],          Stt = stats[DD + c];
        const float Sf  = stats[2 * DD + c], Sff = stats[3 * DD + c];
        const float Stf = stats[4 * DD + c];
        const float mu1  = St * invN;
        const float vart = fmaxf(Stt * invN - mu1 * mu1, 0.f);
        const float muf  = Sf * invN;
        const float varf = fmaxf(Sff * invN - muf * muf, 0.f);
        const float cov  = Stf * invN - mu1 * muf;
        const float r1   = rsqrtf(vart + EPSV);
        const float a1   = bf2f(g1[c]) * r1;
        const float var2 = fmaxf(a1 * a1 * vart + 2.f * a1 * cov + varf, 0.f);
        const float r2   = rsqrtf(var2 + EPSV);
        const float g2r2 = bf2f(g2[c]) * r2;
        sA[c] = g2r2 * a1;
        sB[c] = g2r2;
        sG[c] = bf2f(be2[c]) - g2r2 * (a1 * mu1 + muf);
    }
    __syncthreads();

    float* outf = (float*)out;
    u16*   outb = (u16*)out;
    const size_t P = (size_t)NN * (DD / 2);
    for (size_t i = (size_t)blockIdx.x * blockDim.x + threadIdx.x; i < P;
         i += (size_t)gridDim.x * blockDim.x) {
        const int c = ((int)(i & 63)) * 2;
        const unsigned int tv = *(const unsigned int*)(t + 2 * i);
        const unsigned int fv = *(const unsigned int*)(F + 2 * i);
        const float o0 = sA[c]     * bf2f((u16)(tv & 0xFFFFu))
                       + sB[c]     * bf2f((u16)(fv & 0xFFFFu)) + sG[c];
        const float o1 = sA[c + 1] * bf2f((u16)(tv >> 16))
                       + sB[c + 1] * bf2f((u16)(fv >> 16)) + sG[c + 1];
        if (f32) {
            float2 o; o.x = o0; o.y = o1;
            *(float2*)(outf + 2 * i) = o;
        } else {
            const unsigned int ov = (unsigned int)f2bf(o0) | ((unsigned int)f2bf(o1) << 16);
            *(unsigned int*)(outb + 2 * i) = ov;
        }
    }
}

extern "C" void kernel_launch(void* const* d_in, const int* in_sizes, int n_in,
                              void* d_out, int out_size, void* d_ws, size_t ws_size,
                              hipStream_t stream) {
    const u16* feats = (const u16*)d_in[0];
    const u16* Wg    = (const u16*)d_in[1];
    const u16* bg    = (const u16*)d_in[2];
    const u16* Wr    = (const u16*)d_in[3];
    const u16* br    = (const u16*)d_in[4];
    const u16* g1    = (const u16*)d_in[5];
    // d_in[6] = be1: cancels algebraically, unused
    const u16* g2    = (const u16*)d_in[7];
    const u16* be2   = (const u16*)d_in[8];
    const int* src = (const int*)d_in[9];
    const int* dst = (const int*)d_in[10];

    char* ws = (char*)d_ws;
    u16*   aggb    = (u16*)  ws;                       // 25,600,000 B
    u16*   t       = (u16*)  (ws + 25600000);          // 25,600,000 B
    u16*   feats_c = (u16*)  (ws + 51200000);          // 25,600,000 B
    u16*   pc      = (u16*)  (ws + 76800000);          //     66,816 B
    float* stats   = (float*)(ws + 76866816);          //      2,560 B
    int*   flag    = (int*)  (ws + 76869376);          //          4 B
    int*   counts  = (int*)  (ws + 76869632);          //    400,000 B
    int*   row_st  = (int*)  (ws + 77269632);          //    400,000 B
    int*   cursor  = (int*)  (ws + 77669632);          //    400,000 B
    int*   edge_s  = (int*)  (ws + 78069632);          //  6,400,000 B

    hipMemsetAsync(counts, 0, NN * sizeof(int), stream);
    hipMemsetAsync(stats,  0, 5 * DD * sizeof(float), stream);

    k_detect<<<1, 256, 0, stream>>>((const float*)d_in[0], flag);
    k_convert_feats<<<1024, 256, 0, stream>>>(flag, (const float*)d_in[0], feats_c);
    k_convert_params<<<131, 256, 0, stream>>>(flag,
        (const float*)d_in[1], (const float*)d_in[3], (const float*)d_in[2],
        (const float*)d_in[4], (const float*)d_in[5], (const float*)d_in[7],
        (const float*)d_in[8], pc);

    k_hist<<<1024, 256, 0, stream>>>(dst, counts);
    k_scan<<<1, 1024, 0, stream>>>(counts, row_st, cursor);
    k_fill<<<1024, 256, 0, stream>>>(src, dst, cursor, edge_s);

    k_gather<<<1600, 256, 0, stream>>>(flag, feats, feats_c, edge_s, row_st, counts, aggb);
    k_gemm  <<<1024, 256, 0, stream>>>(flag, aggb, feats, feats_c, Wg, bg, Wr, br, pc, t);
    k_stats <<<400,  256, 0, stream>>>(flag, t, feats, feats_c, stats);
    k_final <<<2048, 256, 0, stream>>>(flag, t, feats, feats_c, g1, g2, be2, pc, stats, d_out);
}

// Round 4
// 432.169 us; speedup vs baseline: 3.5647x; 1.3121x over previous
//
#include <hip/hip_runtime.h>
#include <hip/hip_bf16.h>
#include <stdint.h>

#define NN 100000
#define EE 1600000
#define DD 128
#define EPSV 1e-5f
#define NWIN 8
#define NSCB 98   // ceil(NN/1024)

typedef __attribute__((ext_vector_type(8))) short short8;
typedef __attribute__((ext_vector_type(4))) float floatx4;
typedef unsigned short u16;

union S8 { short8 v; short s[8]; unsigned short u[8]; };

__device__ __forceinline__ float bf2f(u16 u) {
    return __uint_as_float(((unsigned int)u) << 16);
}
__device__ __forceinline__ u16 f2bf(float f) {
    unsigned int x = __float_as_uint(f);
    x += 0x7FFFu + ((x >> 16) & 1u);
    return (u16)(x >> 16);
}

// ---------------------------------------------------------------------------
// ws layout (bytes):
//   aggb     bf16 [NN*DD]  @ 0           (25,600,000)
//   t        bf16 [NN*DD]  @ 25,600,000  (25,600,000)
//   feats_c  bf16 [NN*DD]  @ 51,200,000  (25,600,000)   (only if fp32 inputs)
//   pc       bf16 [33408]  @ 76,800,000  (66,816)
//   stats    fp32 [5*DD]   @ 76,866,816  (2,560)
//   flag     int32         @ 76,869,376  (4)
//   counts   int  [NN]     @ 76,869,632  (400,000)
//   row_st   int  [NN]     @ 77,269,632  (400,000)
//   cursor   int  [NN]     @ 77,669,632  (400,000)
//   edge_s   int  [EE]     @ 78,069,632  (6,400,000)
//   bsum     int  [NSCB]   @ 84,469,632  (512)
//   boff     int  [NSCB]   @ 84,470,144  (512)
// ---------------------------------------------------------------------------

// ------------- dtype detection: fp32 vs bf16 --------------------------------
__global__ void k_detect(const float* __restrict__ f, int* __restrict__ flag) {
    __shared__ int cnt;
    if (threadIdx.x == 0) cnt = 0;
    __syncthreads();
    const float v = fabsf(f[threadIdx.x]);
    if (v > 1e-3f && v < 1e3f) atomicAdd(&cnt, 1);
    __syncthreads();
    if (threadIdx.x == 0) *flag = (cnt >= 128) ? 1 : 0;
}

// ------------- fp32 -> bf16 canonicalization (no-op for bf16 inputs) --------
__global__ __launch_bounds__(256) void k_convert_feats(
    const int* __restrict__ flag, const float* __restrict__ ff,
    u16* __restrict__ fc)
{
    if (*flag == 0) return;
    const size_t P = (size_t)NN * (DD / 2);
    for (size_t i = (size_t)blockIdx.x * blockDim.x + threadIdx.x; i < P;
         i += (size_t)gridDim.x * blockDim.x) {
        const float2 v = *(const float2*)(ff + 2 * i);
        const unsigned int o = (unsigned int)f2bf(v.x) | ((unsigned int)f2bf(v.y) << 16);
        *(unsigned int*)(fc + 2 * i) = o;
    }
}

__global__ __launch_bounds__(256) void k_convert_params(
    const int* __restrict__ flag,
    const float* __restrict__ Wg, const float* __restrict__ Wr,
    const float* __restrict__ bg, const float* __restrict__ br,
    const float* __restrict__ g1, const float* __restrict__ g2,
    const float* __restrict__ be2, u16* __restrict__ pc)
{
    if (*flag == 0) return;
    const int i = blockIdx.x * blockDim.x + threadIdx.x;
    if (i >= 33408) return;
    float v;
    if (i < 16384)      v = Wg[i];
    else if (i < 32768) v = Wr[i - 16384];
    else {
        const int j = i - 32768;
        const int a = j >> 7, o = j & 127;
        v = (a == 0) ? bg[o] : (a == 1) ? br[o] : (a == 2) ? g1[o]
          : (a == 3) ? g2[o] : be2[o];
    }
    pc[i] = f2bf(v);
}

// ---------------- CSR build: histogram -> hierarchical scan -> fill ---------
__global__ __launch_bounds__(256) void k_hist(
    const int* __restrict__ dst, int* __restrict__ counts)
{
    const int stride = gridDim.x * blockDim.x;
    for (int e = blockIdx.x * blockDim.x + threadIdx.x; e < EE; e += stride)
        atomicAdd(&counts[dst[e]], 1);
}

// scan1: per-block (1024-elem chunk) local exclusive scan + block totals
__global__ __launch_bounds__(1024) void k_scan1(
    const int* __restrict__ counts, int* __restrict__ row_st,
    int* __restrict__ bsum)
{
    const int tx = threadIdx.x;
    const int lane = tx & 63, w = tx >> 6;
    __shared__ int wsum[16];
    const int i = blockIdx.x * 1024 + tx;
    const int v = (i < NN) ? counts[i] : 0;
    int incl = v;
#pragma unroll
    for (int d = 1; d < 64; d <<= 1) {
        const int n = __shfl_up(incl, d, 64);
        if (lane >= d) incl += n;
    }
    if (lane == 63) wsum[w] = incl;
    __syncthreads();
    if (tx < 16) {
        int s = wsum[tx];
#pragma unroll
        for (int d = 1; d < 16; d <<= 1) {
            const int n = __shfl_up(s, d, 16);
            if ((tx & 15) >= d) s += n;
        }
        wsum[tx] = s;  // inclusive wave-sums
    }
    __syncthreads();
    const int woff = (w == 0) ? 0 : wsum[w - 1];
    if (i < NN) row_st[i] = woff + incl - v;
    if (tx == 0) bsum[blockIdx.x] = wsum[15];
}

// scan2: single small block scans NSCB block totals -> exclusive offsets
__global__ __launch_bounds__(128) void k_scan2(
    const int* __restrict__ bsum, int* __restrict__ boff)
{
    const int tx = threadIdx.x;
    const int lane = tx & 63, w = tx >> 6;
    __shared__ int ws2[2];
    const int v = (tx < NSCB) ? bsum[tx] : 0;
    int incl = v;
#pragma unroll
    for (int d = 1; d < 64; d <<= 1) {
        const int n = __shfl_up(incl, d, 64);
        if (lane >= d) incl += n;
    }
    if (lane == 63) ws2[w] = incl;
    __syncthreads();
    if (w == 1) incl += ws2[0];
    if (tx < NSCB) boff[tx] = incl - v;
}

// scan3: add block offsets, init cursor
__global__ __launch_bounds__(1024) void k_scan3(
    int* __restrict__ row_st, const int* __restrict__ boff,
    int* __restrict__ cursor)
{
    const int i = blockIdx.x * 1024 + threadIdx.x;
    if (i < NN) {
        const int r = row_st[i] + boff[blockIdx.x];
        row_st[i] = r;
        cursor[i] = r;
    }
}

// windowed fill: only edges whose dst is in the current window are scattered,
// so the active edge_s region (~800 KB) stays L2-resident -> dirty lines
// accumulate ~16 writes before writeback (round 3: 106 MB WRITE for 6.4 MB).
__global__ __launch_bounds__(256) void k_fill(
    const int* __restrict__ src, const int* __restrict__ dst,
    int* __restrict__ cursor, int* __restrict__ edge_s)
{
    const int stride = gridDim.x * blockDim.x;
    const int gid = blockIdx.x * blockDim.x + threadIdx.x;
    const int wsz = (NN + NWIN - 1) / NWIN;  // 12500
#pragma unroll 1
    for (int w = 0; w < NWIN; ++w) {
        const int lo = w * wsz, hi = lo + wsz;
        for (int e = gid; e < EE; e += stride) {
            const int d = dst[e];
            if (d >= lo && d < hi) {
                const int pos = atomicAdd(&cursor[d], 1);
                edge_s[pos] = src[e];
            }
        }
    }
}

// ---------------- Kernel A': gather aggregation -----------------------------
// one wave per dst node; lane owns cols {2*lane, 2*lane+1}; edges batched
// 64-wide into lanes then shfl-broadcast 8 at a time for MLP.
__global__ __launch_bounds__(256) void k_gather(
    const int* __restrict__ flag,
    const u16* __restrict__ feats_raw, const u16* __restrict__ feats_c,
    const int* __restrict__ edge_s, const int* __restrict__ row_st,
    const int* __restrict__ counts,
    u16* __restrict__ aggb)
{
    const u16* __restrict__ F = (*flag != 0) ? feats_c : feats_raw;
    const int lane = threadIdx.x & 63;
    const int wave = (blockIdx.x * blockDim.x + threadIdx.x) >> 6;
    const int nw   = (gridDim.x * blockDim.x) >> 6;
    for (int node = wave; node < NN; node += nw) {
        const int rs  = row_st[node];
        const int deg = counts[node];
        float a0 = 0.f, a1 = 0.f;
        for (int base = 0; base < deg; base += 64) {
            const int rem = deg - base;
            const int nb  = rem < 64 ? rem : 64;
            int idx = 0;
            if (lane < nb) idx = edge_s[rs + base + lane];
            int j = 0;
            for (; j + 8 <= nb; j += 8) {
                unsigned int vv[8];
#pragma unroll
                for (int q = 0; q < 8; ++q) {
                    const int s = __shfl(idx, j + q, 64);
                    vv[q] = *(const unsigned int*)(F + (size_t)s * DD + lane * 2);
                }
#pragma unroll
                for (int q = 0; q < 8; ++q) {
                    a0 += bf2f((u16)(vv[q] & 0xFFFFu));
                    a1 += bf2f((u16)(vv[q] >> 16));
                }
            }
            for (; j < nb; ++j) {
                const int s0 = __shfl(idx, j, 64);
                const unsigned int v0 = *(const unsigned int*)(F + (size_t)s0 * DD + lane * 2);
                a0 += bf2f((u16)(v0 & 0xFFFFu));
                a1 += bf2f((u16)(v0 >> 16));
            }
        }
        const unsigned int o = (unsigned int)f2bf(a0) | ((unsigned int)f2bf(a1) << 16);
        *(unsigned int*)(aggb + (size_t)node * DD + lane * 2) = o;
    }
}

// ---------------- Kernel B: fused dual GEMM + relu + add --------------------
__global__ __launch_bounds__(256) void k_gemm(
    const int* __restrict__ flag,
    const u16* __restrict__ aggb,
    const u16* __restrict__ feats_raw, const u16* __restrict__ feats_c,
    const u16* __restrict__ Wg_raw, const u16* __restrict__ bg_raw,
    const u16* __restrict__ Wr_raw, const u16* __restrict__ br_raw,
    const u16* __restrict__ pc,
    u16* __restrict__ t_out)
{
    const bool f32 = (*flag != 0);
    const u16* __restrict__ F  = f32 ? feats_c     : feats_raw;
    const u16* __restrict__ Wg = f32 ? pc          : Wg_raw;
    const u16* __restrict__ Wr = f32 ? pc + 16384  : Wr_raw;
    const u16* __restrict__ bg = f32 ? pc + 32768  : bg_raw;
    const u16* __restrict__ br = f32 ? pc + 32896  : br_raw;

    const int lane = threadIdx.x & 63;
    const int wv   = threadIdx.x >> 6;
    const int l15  = lane & 15;
    const int quad = lane >> 4;
    const int c0 = wv * 16 + l15;
    const int c1 = 64 + wv * 16 + l15;

    S8 fg0[4], fg1[4], fr0[4], fr1[4];
#pragma unroll
    for (int kb = 0; kb < 4; ++kb) {
        const int kr = kb * 32 + quad * 8;
#pragma unroll
        for (int j = 0; j < 8; ++j) {
            fg0[kb].u[j] = Wg[(size_t)(kr + j) * DD + c0];
            fg1[kb].u[j] = Wg[(size_t)(kr + j) * DD + c1];
            fr0[kb].u[j] = Wr[(size_t)(kr + j) * DD + c0];
            fr1[kb].u[j] = Wr[(size_t)(kr + j) * DD + c1];
        }
    }
    const float bgc0 = bf2f(bg[c0]), bgc1 = bf2f(bg[c1]);
    const float brc0 = bf2f(br[c0]), brc1 = bf2f(br[c1]);

    for (int tile = blockIdx.x; tile < NN / 16; tile += gridDim.x) {
        const int row0 = tile * 16;
        const int arow = row0 + l15;
        floatx4 ag0 = {0.f,0.f,0.f,0.f}, ag1 = {0.f,0.f,0.f,0.f};
        floatx4 ar0 = {0.f,0.f,0.f,0.f}, ar1 = {0.f,0.f,0.f,0.f};
#pragma unroll
        for (int kb = 0; kb < 4; ++kb) {
            const int kbase = kb * 32 + quad * 8;
            S8 av, ff;
            av.v = *(const short8*)(aggb + (size_t)arow * DD + kbase);
            ff.v = *(const short8*)(F    + (size_t)arow * DD + kbase);
            ag0 = __builtin_amdgcn_mfma_f32_16x16x32_bf16(av.v, fg0[kb].v, ag0, 0, 0, 0);
            ag1 = __builtin_amdgcn_mfma_f32_16x16x32_bf16(av.v, fg1[kb].v, ag1, 0, 0, 0);
            ar0 = __builtin_amdgcn_mfma_f32_16x16x32_bf16(ff.v, fr0[kb].v, ar0, 0, 0, 0);
            ar1 = __builtin_amdgcn_mfma_f32_16x16x32_bf16(ff.v, fr1[kb].v, ar1, 0, 0, 0);
        }
#pragma unroll
        for (int r = 0; r < 4; ++r) {
            const int row = row0 + quad * 4 + r;
            const float t0 = fmaxf(ag0[r] + bgc0, 0.f) + fmaxf(ar0[r] + brc0, 0.f);
            const float t1 = fmaxf(ag1[r] + bgc1, 0.f) + fmaxf(ar1[r] + brc1, 0.f);
            t_out[(size_t)row * DD + c0] = f2bf(t0);
            t_out[(size_t)row * DD + c1] = f2bf(t1);
        }
    }
}

// ---------------- Kernel C: column stats ------------------------------------
__global__ __launch_bounds__(256) void k_stats(
    const int* __restrict__ flag,
    const u16* __restrict__ t,
    const u16* __restrict__ feats_raw, const u16* __restrict__ feats_c,
    float* __restrict__ stats)
{
    const u16* __restrict__ F = (*flag != 0) ? feats_c : feats_raw;
    const int tx = threadIdx.x;
    const int c2 = (tx & 63) * 2;
    const int rg = tx >> 6;
    float acc[10];
#pragma unroll
    for (int k = 0; k < 10; ++k) acc[k] = 0.f;

    for (int r = blockIdx.x * 4 + rg; r < NN; r += gridDim.x * 4) {
        const unsigned int tv = *(const unsigned int*)(t + (size_t)r * DD + c2);
        const unsigned int fv = *(const unsigned int*)(F + (size_t)r * DD + c2);
        const float t0 = bf2f((u16)(tv & 0xFFFFu));
        const float t1 = bf2f((u16)(tv >> 16));
        const float f0 = bf2f((u16)(fv & 0xFFFFu));
        const float f1 = bf2f((u16)(fv >> 16));
        acc[0] += t0;      acc[1] += t1;
        acc[2] += t0 * t0; acc[3] += t1 * t1;
        acc[4] += f0;      acc[5] += f1;
        acc[6] += f0 * f0; acc[7] += f1 * f1;
        acc[8] += t0 * f0; acc[9] += t1 * f1;
    }

    __shared__ float red[256][10];
#pragma unroll
    for (int k = 0; k < 10; ++k) red[tx][k] = acc[k];
    __syncthreads();
    if (tx < 64) {
#pragma unroll
        for (int k = 0; k < 10; ++k) {
            const float v = red[tx][k] + red[tx + 64][k] + red[tx + 128][k] + red[tx + 192][k];
            unsafeAtomicAdd(&stats[(k >> 1) * DD + c2 + (k & 1)], v);
        }
    }
}

// ---------------- Kernel D: fused BN1+residual+BN2 elementwise --------------
__global__ __launch_bounds__(256) void k_final(
    const int* __restrict__ flag,
    const u16* __restrict__ t,
    const u16* __restrict__ feats_raw, const u16* __restrict__ feats_c,
    const u16* __restrict__ g1_raw, const u16* __restrict__ g2_raw,
    const u16* __restrict__ be2_raw, const u16* __restrict__ pc,
    const float* __restrict__ stats,
    void* __restrict__ out)
{
    const bool f32 = (*flag != 0);
    const u16* __restrict__ F   = f32 ? feats_c    : feats_raw;
    const u16* __restrict__ g1  = f32 ? pc + 33024 : g1_raw;
    const u16* __restrict__ g2  = f32 ? pc + 33152 : g2_raw;
    const u16* __restrict__ be2 = f32 ? pc + 33280 : be2_raw;

    __shared__ float sA[DD], sB[DD], sG[DD];
    if (threadIdx.x < DD) {
        const int c = threadIdx.x;
        const float invN = 1.0f / (float)NN;
        const float St  = stats[c],          Stt = stats[DD + c];
        const float Sf  = stats[2 * DD + c], Sff = stats[3 * DD + c];
        const float Stf = stats[4 * DD + c];
        const float mu1  = St * invN;
        const float vart = fmaxf(Stt * invN - mu1 * mu1, 0.f);
        const float muf  = Sf * invN;
        const float varf = fmaxf(Sff * invN - muf * muf, 0.f);
        const float cov  = Stf * invN - mu1 * muf;
        const float r1   = rsqrtf(vart + EPSV);
        const float a1   = bf2f(g1[c]) * r1;
        const float var2 = fmaxf(a1 * a1 * vart + 2.f * a1 * cov + varf, 0.f);
        const float r2   = rsqrtf(var2 + EPSV);
        const float g2r2 = bf2f(g2[c]) * r2;
        sA[c] = g2r2 * a1;
        sB[c] = g2r2;
        sG[c] = bf2f(be2[c]) - g2r2 * (a1 * mu1 + muf);
    }
    __syncthreads();

    float* outf = (float*)out;
    u16*   outb = (u16*)out;
    const size_t P = (size_t)NN * (DD / 2);
    for (size_t i = (size_t)blockIdx.x * blockDim.x + threadIdx.x; i < P;
         i += (size_t)gridDim.x * blockDim.x) {
        const int c = ((int)(i & 63)) * 2;
        const unsigned int tv = *(const unsigned int*)(t + 2 * i);
        const unsigned int fv = *(const unsigned int*)(F + 2 * i);
        const float o0 = sA[c]     * bf2f((u16)(tv & 0xFFFFu))
                       + sB[c]     * bf2f((u16)(fv & 0xFFFFu)) + sG[c];
        const float o1 = sA[c + 1] * bf2f((u16)(tv >> 16))
                       + sB[c + 1] * bf2f((u16)(fv >> 16)) + sG[c + 1];
        if (f32) {
            float2 o; o.x = o0; o.y = o1;
            *(float2*)(outf + 2 * i) = o;
        } else {
            const unsigned int ov = (unsigned int)f2bf(o0) | ((unsigned int)f2bf(o1) << 16);
            *(unsigned int*)(outb + 2 * i) = ov;
        }
    }
}

extern "C" void kernel_launch(void* const* d_in, const int* in_sizes, int n_in,
                              void* d_out, int out_size, void* d_ws, size_t ws_size,
                              hipStream_t stream) {
    const u16* feats = (const u16*)d_in[0];
    const u16* Wg    = (const u16*)d_in[1];
    const u16* bg    = (const u16*)d_in[2];
    const u16* Wr    = (const u16*)d_in[3];
    const u16* br    = (const u16*)d_in[4];
    const u16* g1    = (const u16*)d_in[5];
    // d_in[6] = be1: cancels algebraically, unused
    const u16* g2    = (const u16*)d_in[7];
    const u16* be2   = (const u16*)d_in[8];
    const int* src = (const int*)d_in[9];
    const int* dst = (const int*)d_in[10];

    char* ws = (char*)d_ws;
    u16*   aggb    = (u16*)  ws;
    u16*   t       = (u16*)  (ws + 25600000);
    u16*   feats_c = (u16*)  (ws + 51200000);
    u16*   pc      = (u16*)  (ws + 76800000);
    float* stats   = (float*)(ws + 76866816);
    int*   flag    = (int*)  (ws + 76869376);
    int*   counts  = (int*)  (ws + 76869632);
    int*   row_st  = (int*)  (ws + 77269632);
    int*   cursor  = (int*)  (ws + 77669632);
    int*   edge_s  = (int*)  (ws + 78069632);
    int*   bsum    = (int*)  (ws + 84469632);
    int*   boff    = (int*)  (ws + 84470144);

    hipMemsetAsync(counts, 0, NN * sizeof(int), stream);
    hipMemsetAsync(stats,  0, 5 * DD * sizeof(float), stream);

    k_detect<<<1, 256, 0, stream>>>((const float*)d_in[0], flag);
    k_convert_feats<<<1024, 256, 0, stream>>>(flag, (const float*)d_in[0], feats_c);
    k_convert_params<<<131, 256, 0, stream>>>(flag,
        (const float*)d_in[1], (const float*)d_in[3], (const float*)d_in[2],
        (const float*)d_in[4], (const float*)d_in[5], (const float*)d_in[7],
        (const float*)d_in[8], pc);

    k_hist <<<1024, 256, 0, stream>>>(dst, counts);
    k_scan1<<<NSCB, 1024, 0, stream>>>(counts, row_st, bsum);
    k_scan2<<<1, 128, 0, stream>>>(bsum, boff);
    k_scan3<<<NSCB, 1024, 0, stream>>>(row_st, boff, cursor);
    k_fill <<<2048, 256, 0, stream>>>(src, dst, cursor, edge_s);

    k_gather<<<2048, 256, 0, stream>>>(flag, feats, feats_c, edge_s, row_st, counts, aggb);
    k_gemm  <<<1024, 256, 0, stream>>>(flag, aggb, feats, feats_c, Wg, bg, Wr, br, pc, t);
    k_stats <<<400,  256, 0, stream>>>(flag, t, feats, feats_c, stats);
    k_final <<<2048, 256, 0, stream>>>(flag, t, feats, feats_c, g1, g2, be2, pc, stats, d_out);
}

// Round 5
// 428.688 us; speedup vs baseline: 3.5936x; 1.0081x over previous
//
#include <hip/hip_runtime.h>
#include <hip/hip_bf16.h>
#include <stdint.h>

#define NN 100000
#define EE 1600000
#define DD 128
#define EPSV 1e-5f
#define NWIN 8          // == XCD count; window w owned by blocks with blockIdx&7==w
#define WSZ 12500       // NN / NWIN (exact)
#define NSCB 98         // ceil(NN/1024)

typedef __attribute__((ext_vector_type(8))) short short8;
typedef __attribute__((ext_vector_type(4))) float floatx4;
typedef unsigned short u16;

union S8 { short8 v; short s[8]; unsigned short u[8]; };

__device__ __forceinline__ float bf2f(u16 u) {
    return __uint_as_float(((unsigned int)u) << 16);
}
__device__ __forceinline__ u16 f2bf(float f) {
    unsigned int x = __float_as_uint(f);
    x += 0x7FFFu + ((x >> 16) & 1u);
    return (u16)(x >> 16);
}

// ---------------------------------------------------------------------------
// ws layout (bytes):
//   aggb     bf16 [NN*DD]  @ 0           (25,600,000)
//   t        bf16 [NN*DD]  @ 25,600,000  (25,600,000)
//   feats_c  bf16 [NN*DD]  @ 51,200,000  (25,600,000)   (only if fp32 inputs)
//   pc       bf16 [33408]  @ 76,800,000  (66,816)
//   stats    fp32 [5*DD]   @ 76,866,816  (2,560)
//   flag     int32         @ 76,869,376  (4)
//   counts   int  [NN]     @ 76,869,632  (400,000)
//   row_st   int  [NN]     @ 77,269,632  (400,000)
//   cursor   int  [NN]     @ 77,669,632  (400,000)
//   edge_s   int  [EE]     @ 78,069,632  (6,400,000)
//   bsum     int  [NSCB]   @ 84,469,632  (512)
//   boff     int  [NSCB]   @ 84,470,144  (512)
// ---------------------------------------------------------------------------

// ------------- dtype detection: fp32 vs bf16 --------------------------------
__global__ void k_detect(const float* __restrict__ f, int* __restrict__ flag) {
    __shared__ int cnt;
    if (threadIdx.x == 0) cnt = 0;
    __syncthreads();
    const float v = fabsf(f[threadIdx.x]);
    if (v > 1e-3f && v < 1e3f) atomicAdd(&cnt, 1);
    __syncthreads();
    if (threadIdx.x == 0) *flag = (cnt >= 128) ? 1 : 0;
}

// ------------- fp32 -> bf16 canonicalization (no-op for bf16 inputs) --------
__global__ __launch_bounds__(256) void k_convert_feats(
    const int* __restrict__ flag, const float* __restrict__ ff,
    u16* __restrict__ fc)
{
    if (*flag == 0) return;
    const size_t P = (size_t)NN * (DD / 2);
    for (size_t i = (size_t)blockIdx.x * blockDim.x + threadIdx.x; i < P;
         i += (size_t)gridDim.x * blockDim.x) {
        const float2 v = *(const float2*)(ff + 2 * i);
        const unsigned int o = (unsigned int)f2bf(v.x) | ((unsigned int)f2bf(v.y) << 16);
        *(unsigned int*)(fc + 2 * i) = o;
    }
}

__global__ __launch_bounds__(256) void k_convert_params(
    const int* __restrict__ flag,
    const float* __restrict__ Wg, const float* __restrict__ Wr,
    const float* __restrict__ bg, const float* __restrict__ br,
    const float* __restrict__ g1, const float* __restrict__ g2,
    const float* __restrict__ be2, u16* __restrict__ pc)
{
    if (*flag == 0) return;
    const int i = blockIdx.x * blockDim.x + threadIdx.x;
    if (i >= 33408) return;
    float v;
    if (i < 16384)      v = Wg[i];
    else if (i < 32768) v = Wr[i - 16384];
    else {
        const int j = i - 32768;
        const int a = j >> 7, o = j & 127;
        v = (a == 0) ? bg[o] : (a == 1) ? br[o] : (a == 2) ? g1[o]
          : (a == 3) ? g2[o] : be2[o];
    }
    pc[i] = f2bf(v);
}

// ---------------- CSR build: XCD-partitioned hist -> scan -> fill -----------
// Each XCD (blockIdx&7) owns dst window [xcd*WSZ, (xcd+1)*WSZ): all counts /
// edge_s lines in that window are written by ONE XCD's L2, so scattered
// writes accumulate in-cache instead of 8 partial-line writebacks (round 4:
// 90 MB WRITE for a 6.4 MB payload even after plain windowing).
__global__ __launch_bounds__(256) void k_hist(
    const int* __restrict__ dst, int* __restrict__ counts)
{
    const int xcd = blockIdx.x & 7;
    const int lo = xcd * WSZ, hi = lo + WSZ;
    const int gid    = (blockIdx.x >> 3) * blockDim.x + threadIdx.x;
    const int stride = (gridDim.x >> 3) * blockDim.x;
    const int4* __restrict__ dst4 = (const int4*)dst;
    for (int e = gid; e < EE / 4; e += stride) {
        const int4 d = dst4[e];
        if (d.x >= lo && d.x < hi) atomicAdd(&counts[d.x], 1);
        if (d.y >= lo && d.y < hi) atomicAdd(&counts[d.y], 1);
        if (d.z >= lo && d.z < hi) atomicAdd(&counts[d.z], 1);
        if (d.w >= lo && d.w < hi) atomicAdd(&counts[d.w], 1);
    }
}

// scan1: per-block (1024-elem chunk) local exclusive scan + block totals
__global__ __launch_bounds__(1024) void k_scan1(
    const int* __restrict__ counts, int* __restrict__ row_st,
    int* __restrict__ bsum)
{
    const int tx = threadIdx.x;
    const int lane = tx & 63, w = tx >> 6;
    __shared__ int wsum[16];
    const int i = blockIdx.x * 1024 + tx;
    const int v = (i < NN) ? counts[i] : 0;
    int incl = v;
#pragma unroll
    for (int d = 1; d < 64; d <<= 1) {
        const int n = __shfl_up(incl, d, 64);
        if (lane >= d) incl += n;
    }
    if (lane == 63) wsum[w] = incl;
    __syncthreads();
    if (tx < 16) {
        int s = wsum[tx];
#pragma unroll
        for (int d = 1; d < 16; d <<= 1) {
            const int n = __shfl_up(s, d, 16);
            if ((tx & 15) >= d) s += n;
        }
        wsum[tx] = s;
    }
    __syncthreads();
    const int woff = (w == 0) ? 0 : wsum[w - 1];
    if (i < NN) row_st[i] = woff + incl - v;
    if (tx == 0) bsum[blockIdx.x] = wsum[15];
}

// scan2: single small block scans NSCB block totals -> exclusive offsets
__global__ __launch_bounds__(128) void k_scan2(
    const int* __restrict__ bsum, int* __restrict__ boff)
{
    const int tx = threadIdx.x;
    const int lane = tx & 63, w = tx >> 6;
    __shared__ int ws2[2];
    const int v = (tx < NSCB) ? bsum[tx] : 0;
    int incl = v;
#pragma unroll
    for (int d = 1; d < 64; d <<= 1) {
        const int n = __shfl_up(incl, d, 64);
        if (lane >= d) incl += n;
    }
    if (lane == 63) ws2[w] = incl;
    __syncthreads();
    if (w == 1) incl += ws2[0];
    if (tx < NSCB) boff[tx] = incl - v;
}

// scan3: add block offsets, init cursor
__global__ __launch_bounds__(1024) void k_scan3(
    int* __restrict__ row_st, const int* __restrict__ boff,
    int* __restrict__ cursor)
{
    const int i = blockIdx.x * 1024 + threadIdx.x;
    if (i < NN) {
        const int r = row_st[i] + boff[blockIdx.x];
        row_st[i] = r;
        cursor[i] = r;
    }
}

// XCD-partitioned fill (see k_hist comment)
__global__ __launch_bounds__(256) void k_fill(
    const int* __restrict__ src, const int* __restrict__ dst,
    int* __restrict__ cursor, int* __restrict__ edge_s)
{
    const int xcd = blockIdx.x & 7;
    const int lo = xcd * WSZ, hi = lo + WSZ;
    const int gid    = (blockIdx.x >> 3) * blockDim.x + threadIdx.x;
    const int stride = (gridDim.x >> 3) * blockDim.x;
    const int4* __restrict__ dst4 = (const int4*)dst;
    const int4* __restrict__ src4 = (const int4*)src;
    for (int e = gid; e < EE / 4; e += stride) {
        const int4 d = dst4[e];
        const int4 s = src4[e];
        if (d.x >= lo && d.x < hi) edge_s[atomicAdd(&cursor[d.x], 1)] = s.x;
        if (d.y >= lo && d.y < hi) edge_s[atomicAdd(&cursor[d.y], 1)] = s.y;
        if (d.z >= lo && d.z < hi) edge_s[atomicAdd(&cursor[d.z], 1)] = s.z;
        if (d.w >= lo && d.w < hi) edge_s[atomicAdd(&cursor[d.w], 1)] = s.w;
    }
}

// ---------------- Kernel A': gather aggregation -----------------------------
__global__ __launch_bounds__(256) void k_gather(
    const int* __restrict__ flag,
    const u16* __restrict__ feats_raw, const u16* __restrict__ feats_c,
    const int* __restrict__ edge_s, const int* __restrict__ row_st,
    const int* __restrict__ counts,
    u16* __restrict__ aggb)
{
    const u16* __restrict__ F = (*flag != 0) ? feats_c : feats_raw;
    const int lane = threadIdx.x & 63;
    const int wave = (blockIdx.x * blockDim.x + threadIdx.x) >> 6;
    const int nw   = (gridDim.x * blockDim.x) >> 6;
    for (int node = wave; node < NN; node += nw) {
        const int rs  = row_st[node];
        const int deg = counts[node];
        float a0 = 0.f, a1 = 0.f;
        for (int base = 0; base < deg; base += 64) {
            const int rem = deg - base;
            const int nb  = rem < 64 ? rem : 64;
            int idx = 0;
            if (lane < nb) idx = edge_s[rs + base + lane];
            int j = 0;
            for (; j + 8 <= nb; j += 8) {
                unsigned int vv[8];
#pragma unroll
                for (int q = 0; q < 8; ++q) {
                    const int s = __shfl(idx, j + q, 64);
                    vv[q] = *(const unsigned int*)(F + (size_t)s * DD + lane * 2);
                }
#pragma unroll
                for (int q = 0; q < 8; ++q) {
                    a0 += bf2f((u16)(vv[q] & 0xFFFFu));
                    a1 += bf2f((u16)(vv[q] >> 16));
                }
            }
            for (; j < nb; ++j) {
                const int s0 = __shfl(idx, j, 64);
                const unsigned int v0 = *(const unsigned int*)(F + (size_t)s0 * DD + lane * 2);
                a0 += bf2f((u16)(v0 & 0xFFFFu));
                a1 += bf2f((u16)(v0 >> 16));
            }
        }
        const unsigned int o = (unsigned int)f2bf(a0) | ((unsigned int)f2bf(a1) << 16);
        *(unsigned int*)(aggb + (size_t)node * DD + lane * 2) = o;
    }
}

// ---------------- Kernel B: fused dual GEMM + relu + add --------------------
__global__ __launch_bounds__(256) void k_gemm(
    const int* __restrict__ flag,
    const u16* __restrict__ aggb,
    const u16* __restrict__ feats_raw, const u16* __restrict__ feats_c,
    const u16* __restrict__ Wg_raw, const u16* __restrict__ bg_raw,
    const u16* __restrict__ Wr_raw, const u16* __restrict__ br_raw,
    const u16* __restrict__ pc,
    u16* __restrict__ t_out)
{
    const bool f32 = (*flag != 0);
    const u16* __restrict__ F  = f32 ? feats_c     : feats_raw;
    const u16* __restrict__ Wg = f32 ? pc          : Wg_raw;
    const u16* __restrict__ Wr = f32 ? pc + 16384  : Wr_raw;
    const u16* __restrict__ bg = f32 ? pc + 32768  : bg_raw;
    const u16* __restrict__ br = f32 ? pc + 32896  : br_raw;

    const int lane = threadIdx.x & 63;
    const int wv   = threadIdx.x >> 6;
    const int l15  = lane & 15;
    const int quad = lane >> 4;
    const int c0 = wv * 16 + l15;
    const int c1 = 64 + wv * 16 + l15;

    S8 fg0[4], fg1[4], fr0[4], fr1[4];
#pragma unroll
    for (int kb = 0; kb < 4; ++kb) {
        const int kr = kb * 32 + quad * 8;
#pragma unroll
        for (int j = 0; j < 8; ++j) {
            fg0[kb].u[j] = Wg[(size_t)(kr + j) * DD + c0];
            fg1[kb].u[j] = Wg[(size_t)(kr + j) * DD + c1];
            fr0[kb].u[j] = Wr[(size_t)(kr + j) * DD + c0];
            fr1[kb].u[j] = Wr[(size_t)(kr + j) * DD + c1];
        }
    }
    const float bgc0 = bf2f(bg[c0]), bgc1 = bf2f(bg[c1]);
    const float brc0 = bf2f(br[c0]), brc1 = bf2f(br[c1]);

    for (int tile = blockIdx.x; tile < NN / 16; tile += gridDim.x) {
        const int row0 = tile * 16;
        const int arow = row0 + l15;
        floatx4 ag0 = {0.f,0.f,0.f,0.f}, ag1 = {0.f,0.f,0.f,0.f};
        floatx4 ar0 = {0.f,0.f,0.f,0.f}, ar1 = {0.f,0.f,0.f,0.f};
#pragma unroll
        for (int kb = 0; kb < 4; ++kb) {
            const int kbase = kb * 32 + quad * 8;
            S8 av, ff;
            av.v = *(const short8*)(aggb + (size_t)arow * DD + kbase);
            ff.v = *(const short8*)(F    + (size_t)arow * DD + kbase);
            ag0 = __builtin_amdgcn_mfma_f32_16x16x32_bf16(av.v, fg0[kb].v, ag0, 0, 0, 0);
            ag1 = __builtin_amdgcn_mfma_f32_16x16x32_bf16(av.v, fg1[kb].v, ag1, 0, 0, 0);
            ar0 = __builtin_amdgcn_mfma_f32_16x16x32_bf16(ff.v, fr0[kb].v, ar0, 0, 0, 0);
            ar1 = __builtin_amdgcn_mfma_f32_16x16x32_bf16(ff.v, fr1[kb].v, ar1, 0, 0, 0);
        }
#pragma unroll
        for (int r = 0; r < 4; ++r) {
            const int row = row0 + quad * 4 + r;
            const float t0 = fmaxf(ag0[r] + bgc0, 0.f) + fmaxf(ar0[r] + brc0, 0.f);
            const float t1 = fmaxf(ag1[r] + bgc1, 0.f) + fmaxf(ar1[r] + brc1, 0.f);
            t_out[(size_t)row * DD + c0] = f2bf(t0);
            t_out[(size_t)row * DD + c1] = f2bf(t1);
        }
    }
}

// ---------------- Kernel C: column stats ------------------------------------
__global__ __launch_bounds__(256) void k_stats(
    const int* __restrict__ flag,
    const u16* __restrict__ t,
    const u16* __restrict__ feats_raw, const u16* __restrict__ feats_c,
    float* __restrict__ stats)
{
    const u16* __restrict__ F = (*flag != 0) ? feats_c : feats_raw;
    const int tx = threadIdx.x;
    const int c2 = (tx & 63) * 2;
    const int rg = tx >> 6;
    float acc[10];
#pragma unroll
    for (int k = 0; k < 10; ++k) acc[k] = 0.f;

    for (int r = blockIdx.x * 4 + rg; r < NN; r += gridDim.x * 4) {
        const unsigned int tv = *(const unsigned int*)(t + (size_t)r * DD + c2);
        const unsigned int fv = *(const unsigned int*)(F + (size_t)r * DD + c2);
        const float t0 = bf2f((u16)(tv & 0xFFFFu));
        const float t1 = bf2f((u16)(tv >> 16));
        const float f0 = bf2f((u16)(fv & 0xFFFFu));
        const float f1 = bf2f((u16)(fv >> 16));
        acc[0] += t0;      acc[1] += t1;
        acc[2] += t0 * t0; acc[3] += t1 * t1;
        acc[4] += f0;      acc[5] += f1;
        acc[6] += f0 * f0; acc[7] += f1 * f1;
        acc[8] += t0 * f0; acc[9] += t1 * f1;
    }

    __shared__ float red[256][10];
#pragma unroll
    for (int k = 0; k < 10; ++k) red[tx][k] = acc[k];
    __syncthreads();
    if (tx < 64) {
#pragma unroll
        for (int k = 0; k < 10; ++k) {
            const float v = red[tx][k] + red[tx + 64][k] + red[tx + 128][k] + red[tx + 192][k];
            unsafeAtomicAdd(&stats[(k >> 1) * DD + c2 + (k & 1)], v);
        }
    }
}

// ---------------- Kernel D: fused BN1+residual+BN2 elementwise --------------
__global__ __launch_bounds__(256) void k_final(
    const int* __restrict__ flag,
    const u16* __restrict__ t,
    const u16* __restrict__ feats_raw, const u16* __restrict__ feats_c,
    const u16* __restrict__ g1_raw, const u16* __restrict__ g2_raw,
    const u16* __restrict__ be2_raw, const u16* __restrict__ pc,
    const float* __restrict__ stats,
    void* __restrict__ out)
{
    const bool f32 = (*flag != 0);
    const u16* __restrict__ F   = f32 ? feats_c    : feats_raw;
    const u16* __restrict__ g1  = f32 ? pc + 33024 : g1_raw;
    const u16* __restrict__ g2  = f32 ? pc + 33152 : g2_raw;
    const u16* __restrict__ be2 = f32 ? pc + 33280 : be2_raw;

    __shared__ float sA[DD], sB[DD], sG[DD];
    if (threadIdx.x < DD) {
        const int c = threadIdx.x;
        const float invN = 1.0f / (float)NN;
        const float St  = stats[c],          Stt = stats[DD + c];
        const float Sf  = stats[2 * DD + c], Sff = stats[3 * DD + c];
        const float Stf = stats[4 * DD + c];
        const float mu1  = St * invN;
        const float vart = fmaxf(Stt * invN - mu1 * mu1, 0.f);
        const float muf  = Sf * invN;
        const float varf = fmaxf(Sff * invN - muf * muf, 0.f);
        const float cov  = Stf * invN - mu1 * muf;
        const float r1   = rsqrtf(vart + EPSV);
        const float a1   = bf2f(g1[c]) * r1;
        const float var2 = fmaxf(a1 * a1 * vart + 2.f * a1 * cov + varf, 0.f);
        const float r2   = rsqrtf(var2 + EPSV);
        const float g2r2 = bf2f(g2[c]) * r2;
        sA[c] = g2r2 * a1;
        sB[c] = g2r2;
        sG[c] = bf2f(be2[c]) - g2r2 * (a1 * mu1 + muf);
    }
    __syncthreads();

    float* outf = (float*)out;
    u16*   outb = (u16*)out;
    const size_t P = (size_t)NN * (DD / 2);
    for (size_t i = (size_t)blockIdx.x * blockDim.x + threadIdx.x; i < P;
         i += (size_t)gridDim.x * blockDim.x) {
        const int c = ((int)(i & 63)) * 2;
        const unsigned int tv = *(const unsigned int*)(t + 2 * i);
        const unsigned int fv = *(const unsigned int*)(F + 2 * i);
        const float o0 = sA[c]     * bf2f((u16)(tv & 0xFFFFu))
                       + sB[c]     * bf2f((u16)(fv & 0xFFFFu)) + sG[c];
        const float o1 = sA[c + 1] * bf2f((u16)(tv >> 16))
                       + sB[c + 1] * bf2f((u16)(fv >> 16)) + sG[c + 1];
        if (f32) {
            float2 o; o.x = o0; o.y = o1;
            *(float2*)(outf + 2 * i) = o;
        } else {
            const unsigned int ov = (unsigned int)f2bf(o0) | ((unsigned int)f2bf(o1) << 16);
            *(unsigned int*)(outb + 2 * i) = ov;
        }
    }
}

extern "C" void kernel_launch(void* const* d_in, const int* in_sizes, int n_in,
                              void* d_out, int out_size, void* d_ws, size_t ws_size,
                              hipStream_t stream) {
    const u16* feats = (const u16*)d_in[0];
    const u16* Wg    = (const u16*)d_in[1];
    const u16* bg    = (const u16*)d_in[2];
    const u16* Wr    = (const u16*)d_in[3];
    const u16* br    = (const u16*)d_in[4];
    const u16* g1    = (const u16*)d_in[5];
    // d_in[6] = be1: cancels algebraically, unused
    const u16* g2    = (const u16*)d_in[7];
    const u16* be2   = (const u16*)d_in[8];
    const int* src = (const int*)d_in[9];
    const int* dst = (const int*)d_in[10];

    char* ws = (char*)d_ws;
    u16*   aggb    = (u16*)  ws;
    u16*   t       = (u16*)  (ws + 25600000);
    u16*   feats_c = (u16*)  (ws + 51200000);
    u16*   pc      = (u16*)  (ws + 76800000);
    float* stats   = (float*)(ws + 76866816);
    int*   flag    = (int*)  (ws + 76869376);
    int*   counts  = (int*)  (ws + 76869632);
    int*   row_st  = (int*)  (ws + 77269632);
    int*   cursor  = (int*)  (ws + 77669632);
    int*   edge_s  = (int*)  (ws + 78069632);
    int*   bsum    = (int*)  (ws + 84469632);
    int*   boff    = (int*)  (ws + 84470144);

    hipMemsetAsync(counts, 0, NN * sizeof(int), stream);
    hipMemsetAsync(stats,  0, 5 * DD * sizeof(float), stream);

    k_detect<<<1, 256, 0, stream>>>((const float*)d_in[0], flag);
    k_convert_feats<<<1024, 256, 0, stream>>>(flag, (const float*)d_in[0], feats_c);
    k_convert_params<<<131, 256, 0, stream>>>(flag,
        (const float*)d_in[1], (const float*)d_in[3], (const float*)d_in[2],
        (const float*)d_in[4], (const float*)d_in[5], (const float*)d_in[7],
        (const float*)d_in[8], pc);

    k_hist <<<2048, 256, 0, stream>>>(dst, counts);
    k_scan1<<<NSCB, 1024, 0, stream>>>(counts, row_st, bsum);
    k_scan2<<<1, 128, 0, stream>>>(bsum, boff);
    k_scan3<<<NSCB, 1024, 0, stream>>>(row_st, boff, cursor);
    k_fill <<<2048, 256, 0, stream>>>(src, dst, cursor, edge_s);

    k_gather<<<2048, 256, 0, stream>>>(flag, feats, feats_c, edge_s, row_st, counts, aggb);
    k_gemm  <<<1024, 256, 0, stream>>>(flag, aggb, feats, feats_c, Wg, bg, Wr, br, pc, t);
    k_stats <<<400,  256, 0, stream>>>(flag, t, feats, feats_c, stats);
    k_final <<<2048, 256, 0, stream>>>(flag, t, feats, feats_c, g1, g2, be2, pc, stats, d_out);
}